// Round 9
// baseline (2295.469 us; speedup 1.0000x reference)
//
#include <hip/hip_runtime.h>

// PointConv: B=4, N=16384, K=32, F=64
// out[p,f] = sum_k ( lrelu(rel(p,k) @ W1 + b1) @ W2 + b2 )[f] * x[idx[p,k], f]
//
// Round 13: DECOMPOSITION change. Four nulls (r10 VALU-cut, r11 reg-hoist,
// r8/r12 1- and 2-body pipelines) all flat at ~70us; compiler clamps to
// 104-128 VGPR and collapses any deep pipeline (r12: designed 146 live,
// allocated 104, no scratch). At 2 waves/SIMD nothing covers latency and
// ILP can't be materialized -> make the WAVE lighter instead of the
// schedule deeper:
//  - f-split wave pairs: wave parity c handles features 2m+c only.
//    acc 32->16 regs, xv 32->16/buffer, bfrag reads 8->4, epilogue 32->16.
//    h-MLP (A-operand) duplicated across the pair (+VALU, proven non-binding).
//  - designed live set ~100 unified regs -> __launch_bounds__(256,4) fits
//    BY CONSTRUCTION (r7 failed at ~150 live > 128 cap). 4 waves/SIMD.
//  - 131072 waves, grid 4096 blocks x 4 waves (2 point-streams x 2 c-halves).
// Kept from r10: 2-deep jm pipeline (per-lane idx load serving rel-pos +
// x-rows via bpermute), iteration-old pos addresses, gathers before MFMA,
// 32-bit saddr addressing, xvA/xvB double buffer, b2-folded acc init.
// Gating: WRITE_SIZE ~16MB (spill tripwire). If dur flat at ~70 with
// occupancy doubled -> per-CU shared-resource limit, ablation probe next.

#define NPTS   16384
#define KNB    32
#define F      64
#define BATCH  4
#define LOG2N  14
#define WPTS   8

typedef _Float16 h2     __attribute__((ext_vector_type(2)));
typedef _Float16 h8     __attribute__((ext_vector_type(8)));
typedef float    f32x16 __attribute__((ext_vector_type(16)));

__global__ __launch_bounds__(256, 4) void pointconv_mfma(
    const float* __restrict__ x,
    const float* __restrict__ pos,
    const int*   __restrict__ idx,
    const float* __restrict__ W1,
    const float* __restrict__ b1,
    const float* __restrict__ W2,
    const float* __restrict__ b2,
    float*       __restrict__ out)
{
    // w1p[g/2] = {wx,wx', wy,wy', wz,wz', b1,b1'} for g-pair (f16)
    __shared__ __align__(16) _Float16 w1p[32][8];
    // w2f[hf][t][c][m][j] = f16(W2[16t+8hf+j][2m+c]) — fragment-ordered,
    // lanes read consecutive 16B blocks -> conflict-free ds_read_b128
    __shared__ __align__(16) _Float16 w2f[2][4][2][32][8];

    const int tid = threadIdx.x;
    if (tid < 32) {
        const int g = 2 * tid;
        w1p[tid][0] = (_Float16)W1[0 * F + g]; w1p[tid][1] = (_Float16)W1[0 * F + g + 1];
        w1p[tid][2] = (_Float16)W1[1 * F + g]; w1p[tid][3] = (_Float16)W1[1 * F + g + 1];
        w1p[tid][4] = (_Float16)W1[2 * F + g]; w1p[tid][5] = (_Float16)W1[2 * F + g + 1];
        w1p[tid][6] = (_Float16)b1[g];         w1p[tid][7] = (_Float16)b1[g + 1];
    }
#pragma unroll
    for (int r = 0; r < 16; ++r) {             // 4096 elems, coalesced global read
        const int e = r * 256 + tid;           // e = g*64 + f
        const int g = e >> 6, f = e & 63;
        w2f[(g >> 3) & 1][g >> 4][f & 1][f >> 1][g & 7] = (_Float16)W2[e];
    }
    __syncthreads();

    const int lane = tid & 63;
    const int wv   = tid >> 6;
    const int c    = wv & 1;      // feature-interleave half owned by this wave
    const int strm = wv >> 1;     // point stream within block
    const int m    = lane & 31;   // MFMA row (neighbor slot) / f-pair index
    const int hf   = lane >> 5;   // k-half of A/B fragments
    const int voff = hf << 4;     // bpermute byte base (source lane 4*hf + rA)
    const uint32_t mc = 2u * (uint32_t)m + (uint32_t)c;   // this wave's feature

    const float b2s = b2[mc];

    const int p0   = (blockIdx.x * 2 + strm) * WPTS;
    const int p0_s = __builtin_amdgcn_readfirstlane(p0);
    const int base = (p0_s >> LOG2N) << LOG2N;                     // b*N

    const h2 c01 = { (_Float16)0.1f, (_Float16)0.1f };

    // ---- prologue: point p0's rel-pos raw loads, x-gathers; jm for p0+1 ----
    float xvA[16], xvB[16];       // 16 scalar x values (this wave's feature)
    float rlA[6], rlB[6];         // {nbr x,y,z, own x,y,z} raw loads, sub at use
    int   jmA = 0, jmB = 0;       // idx[p][m] pipeline (2 deep)
    {
        const int jm0 = idx[(uint32_t)(p0_s * KNB) + (uint32_t)m];
#pragma unroll
        for (int reg = 0; reg < 16; ++reg) {
            const int rA = (reg & 3) + ((reg >> 2) << 3);
            const int jk = __builtin_amdgcn_ds_bpermute(voff + 4 * rA, jm0);
            xvA[reg] = x[((uint32_t)(base + jk) << 6) + mc];
        }
        const uint32_t nr3 = 3u * (uint32_t)(base + jm0);
        const uint32_t pp3 = 3u * (uint32_t)p0_s;
        rlA[0] = pos[nr3];     rlA[1] = pos[nr3 + 1]; rlA[2] = pos[nr3 + 2];
        rlA[3] = pos[pp3];     rlA[4] = pos[pp3 + 1]; rlA[5] = pos[pp3 + 2];
        if (WPTS > 1) jmA = idx[(uint32_t)((p0_s + 1) * KNB) + (uint32_t)m];
    }

    // Per iteration (output point p = p0+I):
    //   JM_CUR = idx row p+1 (loaded iter I-1)   JM_NXT <- idx row p+2
    //   RL_CUR = pos raw loads for p (iter I-1)  RL_NXT <- pos loads for p+1
    //   XV_CUR = x vals for p (iter I-1)         XV_NXT <- x vals for p+1
#define POINT_BODY(XV_CUR, XV_NXT, JM_CUR, JM_NXT, RL_CUR, RL_NXT, I)         \
    {                                                                         \
        const int p_s = p0_s + (I);                                           \
        /* (1) idx row p+2, per-lane, no deps */                              \
        if ((I) + 2 < WPTS)                                                   \
            JM_NXT = idx[(uint32_t)((p_s + 2) * KNB) + (uint32_t)m];          \
        /* (2) pos raw loads for p+1 (JM_CUR is an iteration old: ready) */   \
        if ((I) + 1 < WPTS) {                                                 \
            const uint32_t nr3 = 3u * (uint32_t)(base + JM_CUR);              \
            const uint32_t pp3 = 3u * (uint32_t)(p_s + 1);                    \
            RL_NXT[0] = pos[nr3];     RL_NXT[1] = pos[nr3 + 1];               \
            RL_NXT[2] = pos[nr3 + 2];                                         \
            RL_NXT[3] = pos[pp3];     RL_NXT[4] = pos[pp3 + 1];               \
            RL_NXT[5] = pos[pp3 + 2];                                         \
        }                                                                     \
        /* (3) x-gathers for p+1: rows from JM_CUR via bpermute, 4B/lane */   \
        if ((I) + 1 < WPTS) {                                                 \
            _Pragma("unroll")                                                 \
            for (int reg = 0; reg < 16; ++reg) {                              \
                const int rA = (reg & 3) + ((reg >> 2) << 3);                 \
                const int jk = __builtin_amdgcn_ds_bpermute(voff + 4 * rA, JM_CUR); \
                XV_NXT[reg] = x[((uint32_t)(base + jk) << 6) + mc];           \
            }                                                                 \
        }                                                                     \
        /* (4) MFMA phase for p (RL_CUR loads are an iteration old) */        \
        const float rx = RL_CUR[3] - RL_CUR[0];                               \
        const float ry = RL_CUR[4] - RL_CUR[1];                               \
        const float rz = RL_CUR[5] - RL_CUR[2];                               \
        f32x16 acc;                                                           \
        _Pragma("unroll")                                                     \
        for (int r = 0; r < 16; ++r) acc[r] = b2s;                            \
        const h2 rxp = { (_Float16)rx, (_Float16)rx };                        \
        const h2 ryp = { (_Float16)ry, (_Float16)ry };                        \
        const h2 rzp = { (_Float16)rz, (_Float16)rz };                        \
        _Pragma("unroll")                                                     \
        for (int t = 0; t < 4; ++t) {                                         \
            h8 af;                                                            \
            _Pragma("unroll")                                                 \
            for (int jj = 0; jj < 4; ++jj) {                                  \
                const h8 w = *(const h8*)&w1p[8 * t + 4 * hf + jj][0];        \
                const h2 wx = __builtin_shufflevector(w, w, 0, 1);            \
                const h2 wy = __builtin_shufflevector(w, w, 2, 3);            \
                const h2 wz = __builtin_shufflevector(w, w, 4, 5);            \
                const h2 bb = __builtin_shufflevector(w, w, 6, 7);            \
                h2 hv = bb + rxp * wx;                                        \
                hv = hv + ryp * wy;                                           \
                hv = hv + rzp * wz;                                           \
                hv = __builtin_elementwise_max(hv, hv * c01);                 \
                af[2 * jj]     = hv[0];                                       \
                af[2 * jj + 1] = hv[1];                                       \
            }                                                                 \
            const h8 bf = *(const h8*)&w2f[hf][t][c][m][0];                   \
            acc = __builtin_amdgcn_mfma_f32_32x32x16_f16(af, bf, acc, 0, 0, 0); \
        }                                                                     \
        /* (5) epilogue: consume XV_CUR (issued one iteration ago) */         \
        float s0 = 0.f, s1 = 0.f;                                             \
        _Pragma("unroll")                                                     \
        for (int reg = 0; reg < 16; reg += 2) {                               \
            s0 = fmaf(acc[reg],     XV_CUR[reg],     s0);                     \
            s1 = fmaf(acc[reg + 1], XV_CUR[reg + 1], s1);                     \
        }                                                                     \
        float s = s0 + s1;                                                    \
        s += __shfl_xor(s, 32);                                               \
        if (hf == 0)                                                          \
            out[(uint32_t)(p_s * F) + mc] = s;                                \
    }

#pragma unroll 1
    for (int io = 0; io < WPTS; io += 2) {
        POINT_BODY(xvA, xvB, jmA, jmB, rlA, rlB, io);
        POINT_BODY(xvB, xvA, jmB, jmA, rlB, rlA, io + 1);
    }
#undef POINT_BODY
}

extern "C" void kernel_launch(void* const* d_in, const int* in_sizes, int n_in,
                              void* d_out, int out_size, void* d_ws, size_t ws_size,
                              hipStream_t stream) {
    const float* x   = (const float*)d_in[0];
    const float* pos = (const float*)d_in[1];
    const int*   idx = (const int*)  d_in[2];
    const float* W1  = (const float*)d_in[3];
    const float* b1  = (const float*)d_in[4];
    const float* W2  = (const float*)d_in[5];
    const float* b2  = (const float*)d_in[6];
    float* out = (float*)d_out;

    // 4 waves/block = 2 point-streams x 2 feature-halves; WPTS points/stream
    dim3 grid((BATCH * NPTS) / (2 * WPTS));
    dim3 block(256);
    pointconv_mfma<<<grid, block, 0, stream>>>(x, pos, idx, W1, b1, W2, b2, out);
}

// Round 10
// 174.596 us; speedup vs baseline: 13.1473x; 13.1473x over previous
//
#include <hip/hip_runtime.h>

// PointConv: B=4, N=16384, K=32, F=64
// out[p,f] = sum_k ( lrelu(rel(p,k) @ W1 + b1) @ W2 + b2 )[f] * x[idx[p,k], f]
//
// Round 14: r13's spill decoded the allocator law: arch-VGPR budget =
// 256 / waves_per_EU ((256,5)->48, (256,4)->64, (256,3)->84, (256,2)->128
// measured), AGPR accumulators budgeted separately. r13's f-split wave needs
// ~70-80 ARCH regs (acc f32x16 lives in AGPR) -> fits the (256,3) budget of
// 84, not r13's (256,4) budget of 64. Same kernel as r13, launch bound
// (256,3): 3 waves/SIMD, ~1.5-2x TLP vs the 70us plateau kernels.
//  - f-split wave pairs: wave parity c handles features 2m+c only.
//    acc 16 AGPR, xv 16/buffer, bfrag reads 4, epilogue 16 FMA.
//  - h-MLP duplicated across the pair (VALU proven non-binding, r10).
//  - 2-deep jm pipeline, iteration-old pos addresses, gathers before MFMA,
//    32-bit saddr addressing, xvA/xvB double buffer, b2-folded acc init.
// Gating (pre-committed): WRITE_SIZE > 25MB or dur >= 65us -> occupancy
// lever dead; revert to r11 and probe wave-desync or declare ceiling.

#define NPTS   16384
#define KNB    32
#define F      64
#define BATCH  4
#define LOG2N  14
#define WPTS   8

typedef _Float16 h2     __attribute__((ext_vector_type(2)));
typedef _Float16 h8     __attribute__((ext_vector_type(8)));
typedef float    f32x16 __attribute__((ext_vector_type(16)));

__global__ __launch_bounds__(256, 3) void pointconv_mfma(
    const float* __restrict__ x,
    const float* __restrict__ pos,
    const int*   __restrict__ idx,
    const float* __restrict__ W1,
    const float* __restrict__ b1,
    const float* __restrict__ W2,
    const float* __restrict__ b2,
    float*       __restrict__ out)
{
    // w1p[g/2] = {wx,wx', wy,wy', wz,wz', b1,b1'} for g-pair (f16)
    __shared__ __align__(16) _Float16 w1p[32][8];
    // w2f[hf][t][c][m][j] = f16(W2[16t+8hf+j][2m+c]) — fragment-ordered,
    // lanes read consecutive 16B blocks -> conflict-free ds_read_b128
    __shared__ __align__(16) _Float16 w2f[2][4][2][32][8];

    const int tid = threadIdx.x;
    if (tid < 32) {
        const int g = 2 * tid;
        w1p[tid][0] = (_Float16)W1[0 * F + g]; w1p[tid][1] = (_Float16)W1[0 * F + g + 1];
        w1p[tid][2] = (_Float16)W1[1 * F + g]; w1p[tid][3] = (_Float16)W1[1 * F + g + 1];
        w1p[tid][4] = (_Float16)W1[2 * F + g]; w1p[tid][5] = (_Float16)W1[2 * F + g + 1];
        w1p[tid][6] = (_Float16)b1[g];         w1p[tid][7] = (_Float16)b1[g + 1];
    }
#pragma unroll
    for (int r = 0; r < 16; ++r) {             // 4096 elems, coalesced global read
        const int e = r * 256 + tid;           // e = g*64 + f
        const int g = e >> 6, f = e & 63;
        w2f[(g >> 3) & 1][g >> 4][f & 1][f >> 1][g & 7] = (_Float16)W2[e];
    }
    __syncthreads();

    const int lane = tid & 63;
    const int wv   = tid >> 6;
    const int c    = wv & 1;      // feature-interleave half owned by this wave
    const int strm = wv >> 1;     // point stream within block
    const int m    = lane & 31;   // MFMA row (neighbor slot) / f-pair index
    const int hf   = lane >> 5;   // k-half of A/B fragments
    const int voff = hf << 4;     // bpermute byte base (source lane 4*hf + rA)
    const uint32_t mc = 2u * (uint32_t)m + (uint32_t)c;   // this wave's feature

    const float b2s = b2[mc];

    const int p0   = (blockIdx.x * 2 + strm) * WPTS;
    const int p0_s = __builtin_amdgcn_readfirstlane(p0);
    const int base = (p0_s >> LOG2N) << LOG2N;                     // b*N

    const h2 c01 = { (_Float16)0.1f, (_Float16)0.1f };

    // ---- prologue: point p0's rel-pos raw loads, x-gathers; jm for p0+1 ----
    float xvA[16], xvB[16];       // 16 scalar x values (this wave's feature)
    float rlA[6], rlB[6];         // {nbr x,y,z, own x,y,z} raw loads, sub at use
    int   jmA = 0, jmB = 0;       // idx[p][m] pipeline (2 deep)
    {
        const int jm0 = idx[(uint32_t)(p0_s * KNB) + (uint32_t)m];
#pragma unroll
        for (int reg = 0; reg < 16; ++reg) {
            const int rA = (reg & 3) + ((reg >> 2) << 3);
            const int jk = __builtin_amdgcn_ds_bpermute(voff + 4 * rA, jm0);
            xvA[reg] = x[((uint32_t)(base + jk) << 6) + mc];
        }
        const uint32_t nr3 = 3u * (uint32_t)(base + jm0);
        const uint32_t pp3 = 3u * (uint32_t)p0_s;
        rlA[0] = pos[nr3];     rlA[1] = pos[nr3 + 1]; rlA[2] = pos[nr3 + 2];
        rlA[3] = pos[pp3];     rlA[4] = pos[pp3 + 1]; rlA[5] = pos[pp3 + 2];
        if (WPTS > 1) jmA = idx[(uint32_t)((p0_s + 1) * KNB) + (uint32_t)m];
    }

    // Per iteration (output point p = p0+I):
    //   JM_CUR = idx row p+1 (loaded iter I-1)   JM_NXT <- idx row p+2
    //   RL_CUR = pos raw loads for p (iter I-1)  RL_NXT <- pos loads for p+1
    //   XV_CUR = x vals for p (iter I-1)         XV_NXT <- x vals for p+1
#define POINT_BODY(XV_CUR, XV_NXT, JM_CUR, JM_NXT, RL_CUR, RL_NXT, I)         \
    {                                                                         \
        const int p_s = p0_s + (I);                                           \
        /* (1) idx row p+2, per-lane, no deps */                              \
        if ((I) + 2 < WPTS)                                                   \
            JM_NXT = idx[(uint32_t)((p_s + 2) * KNB) + (uint32_t)m];          \
        /* (2) pos raw loads for p+1 (JM_CUR is an iteration old: ready) */   \
        if ((I) + 1 < WPTS) {                                                 \
            const uint32_t nr3 = 3u * (uint32_t)(base + JM_CUR);              \
            const uint32_t pp3 = 3u * (uint32_t)(p_s + 1);                    \
            RL_NXT[0] = pos[nr3];     RL_NXT[1] = pos[nr3 + 1];               \
            RL_NXT[2] = pos[nr3 + 2];                                         \
            RL_NXT[3] = pos[pp3];     RL_NXT[4] = pos[pp3 + 1];               \
            RL_NXT[5] = pos[pp3 + 2];                                         \
        }                                                                     \
        /* (3) x-gathers for p+1: rows from JM_CUR via bpermute, 4B/lane */   \
        if ((I) + 1 < WPTS) {                                                 \
            _Pragma("unroll")                                                 \
            for (int reg = 0; reg < 16; ++reg) {                              \
                const int rA = (reg & 3) + ((reg >> 2) << 3);                 \
                const int jk = __builtin_amdgcn_ds_bpermute(voff + 4 * rA, JM_CUR); \
                XV_NXT[reg] = x[((uint32_t)(base + jk) << 6) + mc];           \
            }                                                                 \
        }                                                                     \
        /* (4) MFMA phase for p (RL_CUR loads are an iteration old) */        \
        const float rx = RL_CUR[3] - RL_CUR[0];                               \
        const float ry = RL_CUR[4] - RL_CUR[1];                               \
        const float rz = RL_CUR[5] - RL_CUR[2];                               \
        f32x16 acc;                                                           \
        _Pragma("unroll")                                                     \
        for (int r = 0; r < 16; ++r) acc[r] = b2s;                            \
        const h2 rxp = { (_Float16)rx, (_Float16)rx };                        \
        const h2 ryp = { (_Float16)ry, (_Float16)ry };                        \
        const h2 rzp = { (_Float16)rz, (_Float16)rz };                        \
        _Pragma("unroll")                                                     \
        for (int t = 0; t < 4; ++t) {                                         \
            h8 af;                                                            \
            _Pragma("unroll")                                                 \
            for (int jj = 0; jj < 4; ++jj) {                                  \
                const h8 w = *(const h8*)&w1p[8 * t + 4 * hf + jj][0];        \
                const h2 wx = __builtin_shufflevector(w, w, 0, 1);            \
                const h2 wy = __builtin_shufflevector(w, w, 2, 3);            \
                const h2 wz = __builtin_shufflevector(w, w, 4, 5);            \
                const h2 bb = __builtin_shufflevector(w, w, 6, 7);            \
                h2 hv = bb + rxp * wx;                                        \
                hv = hv + ryp * wy;                                           \
                hv = hv + rzp * wz;                                           \
                hv = __builtin_elementwise_max(hv, hv * c01);                 \
                af[2 * jj]     = hv[0];                                       \
                af[2 * jj + 1] = hv[1];                                       \
            }                                                                 \
            const h8 bf = *(const h8*)&w2f[hf][t][c][m][0];                   \
            acc = __builtin_amdgcn_mfma_f32_32x32x16_f16(af, bf, acc, 0, 0, 0); \
        }                                                                     \
        /* (5) epilogue: consume XV_CUR (issued one iteration ago) */         \
        float s0 = 0.f, s1 = 0.f;                                             \
        _Pragma("unroll")                                                     \
        for (int reg = 0; reg < 16; reg += 2) {                               \
            s0 = fmaf(acc[reg],     XV_CUR[reg],     s0);                     \
            s1 = fmaf(acc[reg + 1], XV_CUR[reg + 1], s1);                     \
        }                                                                     \
        float s = s0 + s1;                                                    \
        s += __shfl_xor(s, 32);                                               \
        if (hf == 0)                                                          \
            out[(uint32_t)(p_s * F) + mc] = s;                                \
    }

#pragma unroll 1
    for (int io = 0; io < WPTS; io += 2) {
        POINT_BODY(xvA, xvB, jmA, jmB, rlA, rlB, io);
        POINT_BODY(xvB, xvA, jmB, jmA, rlB, rlA, io + 1);
    }
#undef POINT_BODY
}

extern "C" void kernel_launch(void* const* d_in, const int* in_sizes, int n_in,
                              void* d_out, int out_size, void* d_ws, size_t ws_size,
                              hipStream_t stream) {
    const float* x   = (const float*)d_in[0];
    const float* pos = (const float*)d_in[1];
    const int*   idx = (const int*)  d_in[2];
    const float* W1  = (const float*)d_in[3];
    const float* b1  = (const float*)d_in[4];
    const float* W2  = (const float*)d_in[5];
    const float* b2  = (const float*)d_in[6];
    float* out = (float*)d_out;

    // 4 waves/block = 2 point-streams x 2 feature-halves; WPTS points/stream
    dim3 grid((BATCH * NPTS) / (2 * WPTS));
    dim3 block(256);
    pointconv_mfma<<<grid, block, 0, stream>>>(x, pos, idx, W1, b1, W2, b2, out);
}

// Round 11
// 144.221 us; speedup vs baseline: 15.9163x; 1.2106x over previous
//
#include <hip/hip_runtime.h>

// PointConv: B=4, N=16384, K=32, F=64
// out[p,f] = sum_k ( lrelu(rel(p,k) @ W1 + b1) @ W2 + b2 )[f] * x[idx[p,k], f]
//
// Round 15: L1-REQUEST model finally fits ALL data. Per-point 64B-line
// requests: gathers 128 + scattered per-lane pos 192 + idx/own/store 11
// = 331 lines at ~0.5/cyc vs ~1/cyc L1 port. r14 f-split added +195 lines
// -> predicted 1.59x, measured 1.59x (exact). VALU-cut/LDS-hoist/pipeline
// rounds changed no lines -> all flat. Occupancy probes (r14: 30% occ,
// worse) rule out TLP. The wall is scattered-request THROUGHPUT.
// This round removes the dominant scatter source (pos, 58% of lines):
//  - pos[batch] staged in LDS as f16 planes: pxy[N] f16x2 (64KB) +
//    pz[N] f16 (32KB). rel_pos = LDS reads (banked, not L1). 6 scattered
//    global dwords/point -> ~4 LDS reads/point. f16 rel error ~1e-3.
//  - block 512 (8 waves) x WPTS=32 -> 256 points/block, grid=256:
//    staging paid once per CU. LDS total ~105KB (1 block/CU).
//  - launch_bounds(512,2): 2 waves/SIMD, VGPR cap 128 — occupancy and
//    register envelope UNCHANGED vs the 70us kernels (clean A/B on the
//    pos-scatter variable only).
// Kept: 2-deep jm pipeline, bpermute row recovery, gathers-before-MFMA,
// 32-bit saddr addressing, xvA/xvB double buffer, b2-folded acc init.
// Tripwires: WRITE>25MB = spill; dur flat ~70 = request-model dead ->
// revert r11, declare structural plateau.

#define NPTS   16384
#define KNB    32
#define F      64
#define BATCH  4
#define LOG2N  14
#define WPTS   32
#define WAVES  8

typedef _Float16 h2     __attribute__((ext_vector_type(2)));
typedef _Float16 h8     __attribute__((ext_vector_type(8)));
typedef float    f32x16 __attribute__((ext_vector_type(16)));

__global__ __launch_bounds__(512, 2) void pointconv_mfma(
    const float* __restrict__ x,
    const float* __restrict__ pos,
    const int*   __restrict__ idx,
    const float* __restrict__ W1,
    const float* __restrict__ b1,
    const float* __restrict__ W2,
    const float* __restrict__ b2,
    float*       __restrict__ out)
{
    // w1p[g/2] = {wx,wx', wy,wy', wz,wz', b1,b1'} for g-pair (f16)
    __shared__ __align__(16) _Float16 w1p[32][8];
    // w2f[hf][t][c][m][j] = f16(W2[16t+8hf+j][2m+c]) — fragment-ordered,
    // lanes read consecutive 16B blocks -> conflict-free ds_read_b128
    __shared__ __align__(16) _Float16 w2f[2][4][2][32][8];
    // batch pos planes, f16: removes ALL scattered global pos reads
    __shared__ __align__(8) _Float16 pxy[NPTS][2];   // 64 KB
    __shared__ __align__(4) _Float16 pz[NPTS];       // 32 KB

    const int tid = threadIdx.x;                     // 0..511
    if (tid < 32) {
        const int g = 2 * tid;
        w1p[tid][0] = (_Float16)W1[0 * F + g]; w1p[tid][1] = (_Float16)W1[0 * F + g + 1];
        w1p[tid][2] = (_Float16)W1[1 * F + g]; w1p[tid][3] = (_Float16)W1[1 * F + g + 1];
        w1p[tid][4] = (_Float16)W1[2 * F + g]; w1p[tid][5] = (_Float16)W1[2 * F + g + 1];
        w1p[tid][6] = (_Float16)b1[g];         w1p[tid][7] = (_Float16)b1[g + 1];
    }
#pragma unroll
    for (int r = 0; r < 8; ++r) {              // 4096 elems over 512 threads
        const int e = r * 512 + tid;           // e = g*64 + f
        const int g = e >> 6, f = e & 63;
        w2f[(g >> 3) & 1][g >> 4][f & 1][f >> 1][g & 7] = (_Float16)W2[e];
    }
    // pos staging: this block's batch (all 256 points of a block share it)
    {
        const int bb = ((blockIdx.x * (WAVES * WPTS)) >> LOG2N) << LOG2N;
        const float* __restrict__ pb = pos + (size_t)bb * 3;
#pragma unroll 4
        for (int n = tid; n < NPTS; n += 512) {
            const float xx = pb[3 * n + 0];
            const float yy = pb[3 * n + 1];
            const float zz = pb[3 * n + 2];
            pxy[n][0] = (_Float16)xx;
            pxy[n][1] = (_Float16)yy;
            pz[n]     = (_Float16)zz;
        }
    }
    __syncthreads();

    const int lane = tid & 63;
    const int wv   = tid >> 6;    // 0..7
    const int m    = lane & 31;   // MFMA row (neighbor slot) / f-pair index
    const int hf   = lane >> 5;   // k-half of A/B fragments
    const int voff = hf << 4;     // bpermute byte base (source lane 4*hf + rA)
    const uint32_t m2 = 2u * (uint32_t)m;                 // f-pair offset

    const float2 b2v = *(const float2*)(b2 + 2 * m);

    const int p0   = (blockIdx.x * WAVES + wv) * WPTS;
    const int p0_s = __builtin_amdgcn_readfirstlane(p0);
    const int base = (p0_s >> LOG2N) << LOG2N;            // b*N

    const h2 c01 = { (_Float16)0.1f, (_Float16)0.1f };

    // ---- prologue: rel(p0) from LDS, x-gathers(p0); jm for p0+1 ----
    float2   xvA[16], xvB[16];
    _Float16 relA[3], relB[3];    // rel_pos for the CURRENT point, f16
    int      jmA = 0, jmB = 0;    // idx[p][m] pipeline (2 deep)
    {
        const int jm0 = idx[(uint32_t)(p0_s * KNB) + (uint32_t)m];
#pragma unroll
        for (int reg = 0; reg < 16; ++reg) {
            const int rA = (reg & 3) + ((reg >> 2) << 3);
            const int jk = __builtin_amdgcn_ds_bpermute(voff + 4 * rA, jm0);
            const uint32_t xo = ((uint32_t)(base + jk) << 6) + m2;
            xvA[reg] = *(const float2*)(x + xo);
        }
        const int ow = p0_s - base;
        const h2 nxy = *(const h2*)&pxy[jm0][0];
        const h2 oxy = *(const h2*)&pxy[ow][0];
        const h2 rxy = oxy - nxy;
        relA[0] = rxy[0]; relA[1] = rxy[1];
        relA[2] = pz[ow] - pz[jm0];
        jmA = idx[(uint32_t)((p0_s + 1) * KNB) + (uint32_t)m];
    }

    // Per iteration (output point p = p0+I):
    //   JM_CUR = idx row p+1 (loaded iter I-1)   JM_NXT <- idx row p+2
    //   REL_CUR = rel_pos for p (iter I-1, LDS)  REL_NXT <- rel for p+1
    //   XV_CUR = x rows for p (iter I-1)         XV_NXT <- x rows for p+1
#define POINT_BODY(XV_CUR, XV_NXT, JM_CUR, JM_NXT, REL_CUR, REL_NXT, I)       \
    {                                                                         \
        const int p_s = p0_s + (I);                                           \
        /* (1) idx row p+2, per-lane, no deps */                              \
        if ((I) + 2 < WPTS)                                                   \
            JM_NXT = idx[(uint32_t)((p_s + 2) * KNB) + (uint32_t)m];          \
        /* (2) rel_pos for p+1 from LDS (banked reads, zero L1 lines) */      \
        if ((I) + 1 < WPTS) {                                                 \
            const int nb = JM_CUR;                                            \
            const int ow = p_s + 1 - base;                                    \
            const h2 nxy = *(const h2*)&pxy[nb][0];                           \
            const h2 oxy = *(const h2*)&pxy[ow][0];                           \
            const h2 rxy = oxy - nxy;                                         \
            REL_NXT[0] = rxy[0]; REL_NXT[1] = rxy[1];                         \
            REL_NXT[2] = pz[ow] - pz[nb];                                     \
        }                                                                     \
        /* (3) x-gathers for p+1: rows from JM_CUR via bpermute */            \
        if ((I) + 1 < WPTS) {                                                 \
            _Pragma("unroll")                                                 \
            for (int reg = 0; reg < 16; ++reg) {                              \
                const int rA = (reg & 3) + ((reg >> 2) << 3);                 \
                const int jk = __builtin_amdgcn_ds_bpermute(voff + 4 * rA, JM_CUR); \
                const uint32_t xo = ((uint32_t)(base + jk) << 6) + m2;        \
                XV_NXT[reg] = *(const float2*)(x + xo);                       \
            }                                                                 \
        }                                                                     \
        /* (4) MFMA phase for p (REL_CUR computed one body ago) */            \
        f32x16 acc0, acc1;                                                    \
        _Pragma("unroll")                                                     \
        for (int r = 0; r < 16; ++r) { acc0[r] = b2v.x; acc1[r] = b2v.y; }    \
        const h2 rxp = { REL_CUR[0], REL_CUR[0] };                            \
        const h2 ryp = { REL_CUR[1], REL_CUR[1] };                            \
        const h2 rzp = { REL_CUR[2], REL_CUR[2] };                            \
        _Pragma("unroll")                                                     \
        for (int t = 0; t < 4; ++t) {                                         \
            h8 af;                                                            \
            _Pragma("unroll")                                                 \
            for (int jj = 0; jj < 4; ++jj) {                                  \
                const h8 w = *(const h8*)&w1p[8 * t + 4 * hf + jj][0];        \
                const h2 wx = __builtin_shufflevector(w, w, 0, 1);            \
                const h2 wy = __builtin_shufflevector(w, w, 2, 3);            \
                const h2 wz = __builtin_shufflevector(w, w, 4, 5);            \
                const h2 bb = __builtin_shufflevector(w, w, 6, 7);            \
                h2 hv = bb + rxp * wx;                                        \
                hv = hv + ryp * wy;                                           \
                hv = hv + rzp * wz;                                           \
                hv = __builtin_elementwise_max(hv, hv * c01);                 \
                af[2 * jj]     = hv[0];                                       \
                af[2 * jj + 1] = hv[1];                                       \
            }                                                                 \
            const h8 bf0 = *(const h8*)&w2f[hf][t][0][m][0];                  \
            const h8 bf1 = *(const h8*)&w2f[hf][t][1][m][0];                  \
            acc0 = __builtin_amdgcn_mfma_f32_32x32x16_f16(af, bf0, acc0, 0, 0, 0); \
            acc1 = __builtin_amdgcn_mfma_f32_32x32x16_f16(af, bf1, acc1, 0, 0, 0); \
        }                                                                     \
        /* (5) epilogue: consume XV_CUR (issued one body ago) */              \
        float s0 = 0.f, s1 = 0.f;                                             \
        _Pragma("unroll")                                                     \
        for (int reg = 0; reg < 16; ++reg) {                                  \
            s0 = fmaf(acc0[reg], XV_CUR[reg].x, s0);                          \
            s1 = fmaf(acc1[reg], XV_CUR[reg].y, s1);                          \
        }                                                                     \
        s0 += __shfl_xor(s0, 32);                                             \
        s1 += __shfl_xor(s1, 32);                                             \
        if (hf == 0)                                                          \
            *(float2*)(out + (uint32_t)(p_s * F) + m2) = make_float2(s0, s1); \
    }

#pragma unroll 1
    for (int io = 0; io < WPTS; io += 2) {
        POINT_BODY(xvA, xvB, jmA, jmB, relA, relB, io);
        POINT_BODY(xvB, xvA, jmB, jmA, relB, relA, io + 1);
    }
#undef POINT_BODY
}

extern "C" void kernel_launch(void* const* d_in, const int* in_sizes, int n_in,
                              void* d_out, int out_size, void* d_ws, size_t ws_size,
                              hipStream_t stream) {
    const float* x   = (const float*)d_in[0];
    const float* pos = (const float*)d_in[1];
    const int*   idx = (const int*)  d_in[2];
    const float* W1  = (const float*)d_in[3];
    const float* b1  = (const float*)d_in[4];
    const float* W2  = (const float*)d_in[5];
    const float* b2  = (const float*)d_in[6];
    float* out = (float*)d_out;

    // 8 waves/block x 32 points/wave = 256 points/block; grid = 256 blocks
    dim3 grid((BATCH * NPTS) / (WAVES * WPTS));
    dim3 block(512);
    pointconv_mfma<<<grid, block, 0, stream>>>(x, pos, idx, W1, b1, W2, b2, out);
}

// Round 14
// 138.117 us; speedup vs baseline: 16.6197x; 1.0442x over previous
//
#include <hip/hip_runtime.h>

// PointConv: B=4, N=16384, K=32, F=64
// out[p,f] = sum_k ( lrelu(rel(p,k) @ W1 + b1) @ W2 + b2 )[f] * x[idx[p,k], f]
//
// Round 18: r11 base (best verified: 137.3us harness / ~70us rocprof) +
// batch-pinned XCD swizzle (T1). The asm lane (r16 NaN, r17 core-dump) is
// closed. The one never-varied factor across the seven flat structural
// rounds: x-gather L2 locality. Each batch's x slab = 4MB = one XCD L2,
// but default round-robin block->XCD makes every XCD serve all 4 batches
// (16MB in 4MB L2 -> thrash -> FETCH 92MB vs 25MB compulsory, gathers stay
// HBM-latency ~900cyc). Remap: batch b's 512 blocks -> XCDs {2b, 2b+1}
// only (bijective, grid 2048 % 8 == 0):
//   xcd = bid & 7; slot = bid >> 3; batch = xcd >> 1;
//   within = slot*2 + (xcd & 1)   // 0..511 inside the batch
// Each XCD's gather working set = its own 4MB slab -> L2-resident.
// Everything else byte-identical to r11: 2-deep jm pipeline, bpermute row
// recovery, w1r/bfrag hoist attempt, xvA/xvB double buffer, 32-bit saddr
// addressing, b2-folded acc init, (256,2).
// Pre-commit: FETCH drops but dur flat -> issue-structural plateau, declare
// ceiling next round.

#define NPTS   16384
#define KNB    32
#define F      64
#define BATCH  4
#define LOG2N  14
#define WPTS   8

typedef _Float16 h2     __attribute__((ext_vector_type(2)));
typedef _Float16 h8     __attribute__((ext_vector_type(8)));
typedef float    f32x16 __attribute__((ext_vector_type(16)));

__global__ __launch_bounds__(256, 2) void pointconv_mfma(
    const float* __restrict__ x,
    const float* __restrict__ pos,
    const int*   __restrict__ idx,
    const float* __restrict__ W1,
    const float* __restrict__ b1,
    const float* __restrict__ W2,
    const float* __restrict__ b2,
    float*       __restrict__ out)
{
    // w1p[g/2] = {wx,wx', wy,wy', wz,wz', b1,b1'} for g-pair (f16)
    __shared__ __align__(16) _Float16 w1p[32][8];
    // w2f[hf][t][c][m][j] = f16(W2[16t+8hf+j][2m+c]) — fragment-ordered,
    // lanes read consecutive 16B blocks -> conflict-free ds_read_b128
    __shared__ __align__(16) _Float16 w2f[2][4][2][32][8];

    const int tid = threadIdx.x;
    if (tid < 32) {
        const int g = 2 * tid;
        w1p[tid][0] = (_Float16)W1[0 * F + g]; w1p[tid][1] = (_Float16)W1[0 * F + g + 1];
        w1p[tid][2] = (_Float16)W1[1 * F + g]; w1p[tid][3] = (_Float16)W1[1 * F + g + 1];
        w1p[tid][4] = (_Float16)W1[2 * F + g]; w1p[tid][5] = (_Float16)W1[2 * F + g + 1];
        w1p[tid][6] = (_Float16)b1[g];         w1p[tid][7] = (_Float16)b1[g + 1];
    }
#pragma unroll
    for (int r = 0; r < 16; ++r) {             // 4096 elems, coalesced global read
        const int e = r * 256 + tid;           // e = g*64 + f
        const int g = e >> 6, f = e & 63;
        w2f[(g >> 3) & 1][g >> 4][f & 1][f >> 1][g & 7] = (_Float16)W2[e];
    }
    __syncthreads();

    const int lane = tid & 63;
    const int wv   = tid >> 6;
    const int m    = lane & 31;   // MFMA row (neighbor slot) / f-pair index
    const int hf   = lane >> 5;   // k-half of A/B fragments
    const int voff = hf << 4;     // bpermute byte base (source lane 4*hf + rA)

    // ---- loop-invariant fragments -> registers (once) ----
    h8 w1r[16];
#pragma unroll
    for (int t = 0; t < 4; ++t)
#pragma unroll
        for (int jj = 0; jj < 4; ++jj)
            w1r[4 * t + jj] = *(const h8*)&w1p[8 * t + 4 * hf + jj][0];
    h8 bfrag[4][2];
#pragma unroll
    for (int t = 0; t < 4; ++t)
#pragma unroll
        for (int c = 0; c < 2; ++c)
            bfrag[t][c] = *(const h8*)&w2f[hf][t][c][m][0];

    const float2 b2v = *(const float2*)(b2 + 2 * m);

    // ---- batch-pinned XCD swizzle (T1): batch b -> XCDs {2b, 2b+1} ----
    // grid = 2048, 2048 % 8 == 0 -> bijective. Each XCD's x working set
    // becomes exactly its own batch slab (4MB = L2 size).
    const int bid    = blockIdx.x;
    const int xcd    = bid & 7;
    const int slot   = bid >> 3;                 // 0..255
    const int batch  = xcd >> 1;                 // 0..3
    const int within = slot * 2 + (xcd & 1);     // 0..511 inside batch

    const int p0   = batch * NPTS + within * (4 * WPTS) + wv * WPTS;
    const int p0_s = __builtin_amdgcn_readfirstlane(p0);
    const int base = (p0_s >> LOG2N) << LOG2N;                     // b*N
    const uint32_t m2 = 2u * (uint32_t)m;                          // f-pair offset

    const h2 c01 = { (_Float16)0.1f, (_Float16)0.1f };

    // ---- prologue: point p0's rel-pos raw loads, x-gathers; jm for p0+1 ----
    float2 xvA[16], xvB[16];
    float  rlA[6], rlB[6];        // {nbr x,y,z, own x,y,z} raw loads, sub at use
    int    jmA = 0, jmB = 0;      // idx[p][m] pipeline (2 deep)
    {
        const int jm0 = idx[(uint32_t)(p0_s * KNB) + (uint32_t)m];
#pragma unroll
        for (int reg = 0; reg < 16; ++reg) {
            const int rA = (reg & 3) + ((reg >> 2) << 3);
            const int jk = __builtin_amdgcn_ds_bpermute(voff + 4 * rA, jm0);
            const uint32_t xo = ((uint32_t)(base + jk) << 6) + m2;
            xvA[reg] = *(const float2*)(x + xo);
        }
        const uint32_t nr3 = 3u * (uint32_t)(base + jm0);
        const uint32_t pp3 = 3u * (uint32_t)p0_s;
        rlA[0] = pos[nr3];     rlA[1] = pos[nr3 + 1]; rlA[2] = pos[nr3 + 2];
        rlA[3] = pos[pp3];     rlA[4] = pos[pp3 + 1]; rlA[5] = pos[pp3 + 2];
        if (WPTS > 1) jmA = idx[(uint32_t)((p0_s + 1) * KNB) + (uint32_t)m];
    }

    // Per iteration (output point p = p0+I):
    //   JM_CUR = idx row p+1 (loaded iter I-1)   JM_NXT <- idx row p+2
    //   RL_CUR = pos raw loads for p (iter I-1)  RL_NXT <- pos loads for p+1
    //   XV_CUR = x rows for p (iter I-1)         XV_NXT <- x rows for p+1
#define POINT_BODY(XV_CUR, XV_NXT, JM_CUR, JM_NXT, RL_CUR, RL_NXT, I)         \
    {                                                                         \
        const int p_s = p0_s + (I);                                           \
        /* (1) idx row p+2, per-lane, no deps */                              \
        if ((I) + 2 < WPTS)                                                   \
            JM_NXT = idx[(uint32_t)((p_s + 2) * KNB) + (uint32_t)m];          \
        /* (2) pos raw loads for p+1 (JM_CUR is an iteration old: ready) */   \
        if ((I) + 1 < WPTS) {                                                 \
            const uint32_t nr3 = 3u * (uint32_t)(base + JM_CUR);              \
            const uint32_t pp3 = 3u * (uint32_t)(p_s + 1);                    \
            RL_NXT[0] = pos[nr3];     RL_NXT[1] = pos[nr3 + 1];               \
            RL_NXT[2] = pos[nr3 + 2];                                         \
            RL_NXT[3] = pos[pp3];     RL_NXT[4] = pos[pp3 + 1];               \
            RL_NXT[5] = pos[pp3 + 2];                                         \
        }                                                                     \
        /* (3) x-gathers for p+1: rows from JM_CUR via bpermute, 32b offs */  \
        if ((I) + 1 < WPTS) {                                                 \
            _Pragma("unroll")                                                 \
            for (int reg = 0; reg < 16; ++reg) {                              \
                const int rA = (reg & 3) + ((reg >> 2) << 3);                 \
                const int jk = __builtin_amdgcn_ds_bpermute(voff + 4 * rA, JM_CUR); \
                const uint32_t xo = ((uint32_t)(base + jk) << 6) + m2;        \
                XV_NXT[reg] = *(const float2*)(x + xo);                       \
            }                                                                 \
        }                                                                     \
        /* (4) MFMA phase for p (RL_CUR loads are an iteration old) */        \
        const float rx = RL_CUR[3] - RL_CUR[0];                               \
        const float ry = RL_CUR[4] - RL_CUR[1];                               \
        const float rz = RL_CUR[5] - RL_CUR[2];                               \
        f32x16 acc0, acc1;                                                    \
        _Pragma("unroll")                                                     \
        for (int r = 0; r < 16; ++r) { acc0[r] = b2v.x; acc1[r] = b2v.y; }    \
        const h2 rxp = { (_Float16)rx, (_Float16)rx };                        \
        const h2 ryp = { (_Float16)ry, (_Float16)ry };                        \
        const h2 rzp = { (_Float16)rz, (_Float16)rz };                        \
        _Pragma("unroll")                                                     \
        for (int t = 0; t < 4; ++t) {                                         \
            h8 af;                                                            \
            _Pragma("unroll")                                                 \
            for (int jj = 0; jj < 4; ++jj) {                                  \
                const h8 w = w1r[4 * t + jj];                                 \
                const h2 wx = __builtin_shufflevector(w, w, 0, 1);            \
                const h2 wy = __builtin_shufflevector(w, w, 2, 3);            \
                const h2 wz = __builtin_shufflevector(w, w, 4, 5);            \
                const h2 bb = __builtin_shufflevector(w, w, 6, 7);            \
                h2 hv = bb + rxp * wx;                                        \
                hv = hv + ryp * wy;                                           \
                hv = hv + rzp * wz;                                           \
                hv = __builtin_elementwise_max(hv, hv * c01);                 \
                af[2 * jj]     = hv[0];                                       \
                af[2 * jj + 1] = hv[1];                                       \
            }                                                                 \
            acc0 = __builtin_amdgcn_mfma_f32_32x32x16_f16(af, bfrag[t][0], acc0, 0, 0, 0); \
            acc1 = __builtin_amdgcn_mfma_f32_32x32x16_f16(af, bfrag[t][1], acc1, 0, 0, 0); \
        }                                                                     \
        /* (5) epilogue: consume XV_CUR (issued one iteration ago) */         \
        float s0 = 0.f, s1 = 0.f;                                             \
        _Pragma("unroll")                                                     \
        for (int reg = 0; reg < 16; ++reg) {                                  \
            s0 = fmaf(acc0[reg], XV_CUR[reg].x, s0);                          \
            s1 = fmaf(acc1[reg], XV_CUR[reg].y, s1);                          \
        }                                                                     \
        s0 += __shfl_xor(s0, 32);                                             \
        s1 += __shfl_xor(s1, 32);                                             \
        if (hf == 0)                                                          \
            *(float2*)(out + (uint32_t)(p_s * F) + m2) = make_float2(s0, s1); \
    }

#pragma unroll 1
    for (int io = 0; io < WPTS; io += 2) {
        POINT_BODY(xvA, xvB, jmA, jmB, rlA, rlB, io);
        POINT_BODY(xvB, xvA, jmB, jmA, rlB, rlA, io + 1);
    }
#undef POINT_BODY
}

extern "C" void kernel_launch(void* const* d_in, const int* in_sizes, int n_in,
                              void* d_out, int out_size, void* d_ws, size_t ws_size,
                              hipStream_t stream) {
    const float* x   = (const float*)d_in[0];
    const float* pos = (const float*)d_in[1];
    const int*   idx = (const int*)  d_in[2];
    const float* W1  = (const float*)d_in[3];
    const float* b1  = (const float*)d_in[4];
    const float* W2  = (const float*)d_in[5];
    const float* b2  = (const float*)d_in[6];
    float* out = (float*)d_out;

    dim3 grid((BATCH * NPTS) / (4 * WPTS));   // 2048 blocks, % 8 == 0
    dim3 block(256);
    pointconv_mfma<<<grid, block, 0, stream>>>(x, pos, idx, W1, b1, W2, b2, out);
}